// Round 2
// baseline (141.857 us; speedup 1.0000x reference)
//
#include <hip/hip_runtime.h>
#include <hip/hip_bf16.h>

#define N_NODES 8192
#define IN_F 128
#define OUT_F 64
#define ALPHA 0.2f
#define CAP 1024  // max edges per row (expected ~164, binomial max ~230)

// Kernel 1: h = x @ W  [N,64];  hi = h @ a[:64];  hj = h @ a[64:]
__global__ __launch_bounds__(256) void gat_h(
    const float* __restrict__ x, const float* __restrict__ W,
    const float* __restrict__ a, float* __restrict__ h,
    float* __restrict__ hi, float* __restrict__ hj) {
  __shared__ float sW[IN_F * OUT_F];  // 32 KB
  int tid = threadIdx.x;
  for (int i = tid; i < IN_F * OUT_F; i += 256) sW[i] = W[i];
  __syncthreads();

  int f = tid & 63;        // output feature (lane)
  int rloc = tid >> 6;     // wave id 0..3
  float a1 = a[f], a2 = a[OUT_F + f];
  int row0 = blockIdx.x * 32;

  for (int rr = 0; rr < 8; ++rr) {
    int row = row0 + rr * 4 + rloc;
    const float4* xr = (const float4*)(x + (size_t)row * IN_F);
    float acc = 0.f;
#pragma unroll
    for (int k4 = 0; k4 < IN_F / 4; ++k4) {
      float4 xv = xr[k4];  // wave-uniform broadcast load
      acc = fmaf(xv.x, sW[(k4 * 4 + 0) * 64 + f], acc);
      acc = fmaf(xv.y, sW[(k4 * 4 + 1) * 64 + f], acc);
      acc = fmaf(xv.z, sW[(k4 * 4 + 2) * 64 + f], acc);
      acc = fmaf(xv.w, sW[(k4 * 4 + 3) * 64 + f], acc);
    }
    h[(size_t)row * 64 + f] = acc;
    float vi = acc * a1, vj = acc * a2;
#pragma unroll
    for (int o = 32; o >= 1; o >>= 1) {
      vi += __shfl_xor(vi, o);
      vj += __shfl_xor(vj, o);
    }
    if (f == 0) { hi[row] = vi; hj[row] = vj; }
  }
}

// Kernel 2: one block (256 threads) per row.
// Load whole adj row into registers up front (8 float4/thread in flight),
// per-thread edge count -> wave prefix-sum -> ONE LDS atomic per wave,
// then place edges + logits + local max in a single pass.
__global__ __launch_bounds__(256) void gat_row(
    const float* __restrict__ adj, const float* __restrict__ h,
    const float* __restrict__ hi, const float* __restrict__ hj,
    float* __restrict__ out) {
  __shared__ int s_idx[CAP];
  __shared__ float s_w[CAP];
  __shared__ int s_cnt;
  __shared__ float s_redA[4];
  __shared__ float s_redB[4];
  __shared__ float s_part[4][64];

  int tid = threadIdx.x;
  int lane = tid & 63;
  int wid = tid >> 6;
  int row = blockIdx.x;

  if (tid == 0) s_cnt = 0;

  // --- issue all adj loads up front (32 KB/row, coalesced float4) ---
  const float4* arow = (const float4*)(adj + (size_t)row * N_NODES);
  float4 v[8];
#pragma unroll
  for (int it = 0; it < 8; ++it) v[it] = arow[tid + it * 256];

  // --- per-thread edge count ---
  int c = 0;
#pragma unroll
  for (int it = 0; it < 8; ++it) {
    c += (v[it].x > 0.f) + (v[it].y > 0.f) + (v[it].z > 0.f) + (v[it].w > 0.f);
  }

  // --- wave inclusive prefix sum of c ---
  int incl = c;
#pragma unroll
  for (int o = 1; o < 64; o <<= 1) {
    int t = __shfl_up(incl, o);
    if (lane >= o) incl += t;
  }

  __syncthreads();  // s_cnt = 0 visible
  int base = 0;
  if (lane == 63) base = atomicAdd(&s_cnt, incl);  // one atomic per wave
  base = __shfl(base, 63);
  int off = base + incl - c;  // exclusive prefix within block

  // --- place edges, compute leaky-relu logits, track local max ---
  float hii = hi[row];
  float lmax = -1e30f;
#pragma unroll
  for (int it = 0; it < 8; ++it) {
    int jb = (tid + it * 256) * 4;
#define PLACE(comp, dj)                                        \
    if (v[it].comp > 0.f) {                                    \
      int j = jb + dj;                                         \
      float l = hii + hj[j];                                   \
      l = (l > 0.f) ? l : ALPHA * l;                           \
      s_w[off] = l; s_idx[off] = j; ++off;                     \
      lmax = fmaxf(lmax, l);                                   \
    }
    PLACE(x, 0) PLACE(y, 1) PLACE(z, 2) PLACE(w, 3)
#undef PLACE
  }

  // --- block max ---
#pragma unroll
  for (int o = 32; o >= 1; o >>= 1) lmax = fmaxf(lmax, __shfl_xor(lmax, o));
  if (lane == 0) s_redA[wid] = lmax;
  __syncthreads();  // placement + maxes done; s_cnt final
  float bmax = fmaxf(fmaxf(s_redA[0], s_redA[1]), fmaxf(s_redA[2], s_redA[3]));
  int cnt = s_cnt;

  // --- exp + block sum ---
  float lsum = 0.f;
  for (int e = tid; e < cnt; e += 256) {
    float w = __expf(s_w[e] - bmax);
    s_w[e] = w;
    lsum += w;
  }
#pragma unroll
  for (int o = 32; o >= 1; o >>= 1) lsum += __shfl_xor(lsum, o);
  if (lane == 0) s_redB[wid] = lsum;
  __syncthreads();  // s_w exp-values + sums visible
  float bsum = s_redB[0] + s_redB[1] + s_redB[2] + s_redB[3];

  // --- weighted gather of h: 4 edge-groups x 64 features ---
  int f = lane;
  float acc = 0.f;
  for (int e = wid; e < cnt; e += 4) {
    acc += s_w[e] * h[(size_t)s_idx[e] * 64 + f];
  }
  s_part[wid][f] = acc;
  __syncthreads();
  if (tid < 64) {
    float vv = s_part[0][f] + s_part[1][f] + s_part[2][f] + s_part[3][f];
    vv /= bsum;
    vv = (vv > 0.f) ? vv : expm1f(vv);  // ELU
    out[(size_t)row * 64 + f] = vv;
  }
}

extern "C" void kernel_launch(void* const* d_in, const int* in_sizes, int n_in,
                              void* d_out, int out_size, void* d_ws, size_t ws_size,
                              hipStream_t stream) {
  const float* x   = (const float*)d_in[0];  // [8192,128]
  const float* adj = (const float*)d_in[1];  // [8192,8192]
  const float* W   = (const float*)d_in[2];  // [128,64]
  const float* a   = (const float*)d_in[3];  // [128,1]
  float* out = (float*)d_out;                // [8192,64]

  float* h  = (float*)d_ws;                  // 8192*64
  float* hi = h + (size_t)N_NODES * OUT_F;   // 8192
  float* hj = hi + N_NODES;                  // 8192

  gat_h<<<N_NODES / 32, 256, 0, stream>>>(x, W, a, h, hi, hj);
  gat_row<<<N_NODES, 256, 0, stream>>>(adj, h, hi, hj, out);
}

// Round 3
// 83.521 us; speedup vs baseline: 1.6985x; 1.6985x over previous
//
#include <hip/hip_runtime.h>
#include <hip/hip_bf16.h>

#define N_NODES 8192
#define IN_F 128
#define OUT_F 64
#define ALPHA 0.2f
#define CAP 1024  // max edges per row (expected ~164, binomial max ~230)

// Kernel 1: h = x @ W  [N,64];  hi = h @ a[:64];  hj = h @ a[64:]
__global__ __launch_bounds__(256) void gat_h(
    const float* __restrict__ x, const float* __restrict__ W,
    const float* __restrict__ a, float* __restrict__ h,
    float* __restrict__ hi, float* __restrict__ hj) {
  __shared__ float sW[IN_F * OUT_F];  // 32 KB
  int tid = threadIdx.x;
  for (int i = tid; i < IN_F * OUT_F; i += 256) sW[i] = W[i];
  __syncthreads();

  int f = tid & 63;        // output feature (lane)
  int rloc = tid >> 6;     // wave id 0..3
  float a1 = a[f], a2 = a[OUT_F + f];
  int row0 = blockIdx.x * 32;

  for (int rr = 0; rr < 8; ++rr) {
    int row = row0 + rr * 4 + rloc;
    const float4* xr = (const float4*)(x + (size_t)row * IN_F);
    float acc = 0.f;
#pragma unroll
    for (int k4 = 0; k4 < IN_F / 4; ++k4) {
      float4 xv = xr[k4];  // wave-uniform broadcast load
      acc = fmaf(xv.x, sW[(k4 * 4 + 0) * 64 + f], acc);
      acc = fmaf(xv.y, sW[(k4 * 4 + 1) * 64 + f], acc);
      acc = fmaf(xv.z, sW[(k4 * 4 + 2) * 64 + f], acc);
      acc = fmaf(xv.w, sW[(k4 * 4 + 3) * 64 + f], acc);
    }
    h[(size_t)row * 64 + f] = acc;
    float vi = acc * a1, vj = acc * a2;
#pragma unroll
    for (int o = 32; o >= 1; o >>= 1) {
      vi += __shfl_xor(vi, o);
      vj += __shfl_xor(vj, o);
    }
    if (f == 0) { hi[row] = vi; hj[row] = vj; }
  }
}

// Kernel 2: one block (256 threads) per row.
// adj row -> per-thread 32-bit edge mask (loads fully in flight, values
// discarded immediately) -> popc/prefix-sum -> ctz placement -> softmax ->
// 4-accumulator unrolled gather of h.
__global__ __launch_bounds__(256) void gat_row(
    const float* __restrict__ adj, const float* __restrict__ h,
    const float* __restrict__ hi, const float* __restrict__ hj,
    float* __restrict__ out) {
  __shared__ int s_idx[CAP + 64];
  __shared__ float s_w[CAP + 64];
  __shared__ int s_cnt;
  __shared__ float s_redA[4];
  __shared__ float s_redB[4];
  __shared__ float s_part[4][64];

  int tid = threadIdx.x;
  int lane = tid & 63;
  int wid = tid >> 6;
  int row = blockIdx.x;

  if (tid == 0) s_cnt = 0;

  // --- adj row -> 32-bit mask per thread (8 independent dwordx4 loads) ---
  const float4* arow = (const float4*)(adj + (size_t)row * N_NODES);
  unsigned int mask = 0;
#pragma unroll
  for (int it = 0; it < 8; ++it) {
    float4 vv = arow[tid + it * 256];
    mask |= (unsigned int)(vv.x > 0.f) << (it * 4 + 0);
    mask |= (unsigned int)(vv.y > 0.f) << (it * 4 + 1);
    mask |= (unsigned int)(vv.z > 0.f) << (it * 4 + 2);
    mask |= (unsigned int)(vv.w > 0.f) << (it * 4 + 3);
  }
  int c = __popc(mask);

  // --- wave inclusive prefix sum of c ---
  int incl = c;
#pragma unroll
  for (int o = 1; o < 64; o <<= 1) {
    int t = __shfl_up(incl, o);
    if (lane >= o) incl += t;
  }

  __syncthreads();  // s_cnt = 0 visible
  int base = 0;
  if (lane == 63) base = atomicAdd(&s_cnt, incl);  // one atomic per wave
  base = __shfl(base, 63);
  int off = base + incl - c;  // exclusive prefix within block

  // --- place edges via ctz, compute leaky-relu logits, local max ---
  float hii = hi[row];
  float lmax = -1e30f;
  unsigned int m = mask;
  while (m) {
    int b = __ffs(m) - 1;      // bit position 0..31
    m &= m - 1;
    // bit b = component (b&3) of float4 index (tid + (b>>2)*256)
    int j = ((tid + ((b >> 2) << 8)) << 2) + (b & 3);
    float l = hii + hj[j];
    l = (l > 0.f) ? l : ALPHA * l;
    s_w[off] = l;
    s_idx[off] = j;
    ++off;
    lmax = fmaxf(lmax, l);
  }

  // --- block max ---
#pragma unroll
  for (int o = 32; o >= 1; o >>= 1) lmax = fmaxf(lmax, __shfl_xor(lmax, o));
  if (lane == 0) s_redA[wid] = lmax;
  __syncthreads();  // placement + maxes done; s_cnt final
  float bmax = fmaxf(fmaxf(s_redA[0], s_redA[1]), fmaxf(s_redA[2], s_redA[3]));
  int cnt = s_cnt;
  int cnt_pad = (cnt + 15) & ~15;

  // --- exp + block sum; pad tail so gather needs no bounds checks ---
  float lsum = 0.f;
  for (int e = tid; e < cnt; e += 256) {
    float w = __expf(s_w[e] - bmax);
    s_w[e] = w;
    lsum += w;
  }
  for (int e = cnt + tid; e < cnt_pad; e += 256) {
    s_w[e] = 0.f;
    s_idx[e] = 0;
  }
#pragma unroll
  for (int o = 32; o >= 1; o >>= 1) lsum += __shfl_xor(lsum, o);
  if (lane == 0) s_redB[wid] = lsum;
  __syncthreads();  // s_w exp-values + padding + sums visible
  float bsum = s_redB[0] + s_redB[1] + s_redB[2] + s_redB[3];

  // --- weighted gather of h: wave-uniform quads, 4 accumulators ---
  int f = lane;
  float acc0 = 0.f, acc1 = 0.f, acc2 = 0.f, acc3 = 0.f;
  for (int e = wid * 4; e < cnt_pad; e += 16) {
    int4 id = *(const int4*)&s_idx[e];     // wave-uniform broadcast reads
    float4 wv = *(const float4*)&s_w[e];
    acc0 = fmaf(wv.x, h[(size_t)id.x * 64 + f], acc0);
    acc1 = fmaf(wv.y, h[(size_t)id.y * 64 + f], acc1);
    acc2 = fmaf(wv.z, h[(size_t)id.z * 64 + f], acc2);
    acc3 = fmaf(wv.w, h[(size_t)id.w * 64 + f], acc3);
  }
  s_part[wid][f] = (acc0 + acc1) + (acc2 + acc3);
  __syncthreads();
  if (tid < 64) {
    float vv = s_part[0][f] + s_part[1][f] + s_part[2][f] + s_part[3][f];
    vv /= bsum;
    vv = (vv > 0.f) ? vv : expm1f(vv);  // ELU
    out[(size_t)row * 64 + f] = vv;
  }
}

extern "C" void kernel_launch(void* const* d_in, const int* in_sizes, int n_in,
                              void* d_out, int out_size, void* d_ws, size_t ws_size,
                              hipStream_t stream) {
  const float* x   = (const float*)d_in[0];  // [8192,128]
  const float* adj = (const float*)d_in[1];  // [8192,8192]
  const float* W   = (const float*)d_in[2];  // [128,64]
  const float* a   = (const float*)d_in[3];  // [128,1]
  float* out = (float*)d_out;                // [8192,64]

  float* h  = (float*)d_ws;                  // 8192*64
  float* hi = h + (size_t)N_NODES * OUT_F;   // 8192
  float* hj = hi + N_NODES;                  // 8192

  gat_h<<<N_NODES / 32, 256, 0, stream>>>(x, W, a, h, hi, hj);
  gat_row<<<N_NODES, 256, 0, stream>>>(adj, h, hi, hj, out);
}